// Round 1
// baseline (9536.361 us; speedup 1.0000x reference)
//
#include <hip/hip_runtime.h>
#include <hip/hip_bf16.h>

#define B_ 256
#define T_ 256
#define I_ 512
#define H_ 1024
#define G4H 4096
#define K0 1536   // I_ + H_
#define K1 2048   // H_ + H_

typedef _Float16 half8 __attribute__((ext_vector_type(8)));
typedef float floatx4 __attribute__((ext_vector_type(4)));

// ---- prep: concat + convert weights to f16, layout [N=4096][K] row-major ----
__global__ __launch_bounds__(256) void prep_wcat(
    _Float16* __restrict__ dst, const float* __restrict__ Wa,
    const float* __restrict__ Wb, int split, int K, int aPitch, int bPitch) {
  int n = blockIdx.y;
  int k = blockIdx.x * 256 + threadIdx.x;
  float v = (k < split) ? Wa[(size_t)n * aPitch + k]
                        : Wb[(size_t)n * bPitch + (k - split)];
  dst[(size_t)n * K + k] = (_Float16)v;
}

// ---- prep: init h states (f16) and c states (0) ----
__global__ __launch_bounds__(256) void prep_state(
    const float* __restrict__ init, _Float16* __restrict__ h1buf,
    _Float16* __restrict__ h2buf, float* __restrict__ c0, float* __restrict__ c1) {
  int idx = blockIdx.x * 256 + threadIdx.x;   // grid = B_*H_/256
  float v = init[idx];
  h1buf[B_ * H_ + idx] = (_Float16)v;  // slot 1 : h1[-1] = init_hidden
  h2buf[idx] = (_Float16)v;            // slot 0 : h2[-1] = init_hidden
  c0[idx] = 0.f;
  c1[idx] = 0.f;
}

// ---- fused pipelined step: blocks 0..255 -> L0 at t=s ; 256..511 -> L1 at t=s-1
__global__ __launch_bounds__(256) void lstm_step(
    const float* __restrict__ ctx,
    const _Float16* __restrict__ Wc0, const _Float16* __restrict__ Wc1,
    _Float16* __restrict__ h1buf, _Float16* __restrict__ h2buf,
    float* __restrict__ c0buf, float* __restrict__ c1buf,
    float* __restrict__ hF1,
    const float* __restrict__ bih0, const float* __restrict__ bhh0,
    const float* __restrict__ bih1, const float* __restrict__ bhh1,
    int s) {
  const int bid = blockIdx.x;
  const int layer = bid >> 8;
  if (layer == 0 && s == T_) return;   // L0 done after s=255
  if (layer == 1 && s == 0) return;    // L1 starts at s=1
  const int tb = bid & 255;
  const int row0 = (tb >> 6) * 64;     // batch-row tile origin
  const int h0c = (tb & 63) * 16;      // h-chunk origin (16 h per block)
  const int K = layer ? K1 : K0;
  const int nk = K >> 5;               // K/32 stages
  const _Float16* __restrict__ Wc = layer ? Wc1 : Wc0;
  const int rd = (s + 1) & 1;          // read slot parity
  const int wr = s & 1;                // write slot parity
  const _Float16* __restrict__ hin1 = h1buf + rd * (B_ * H_);  // h1[s-1]
  const _Float16* __restrict__ hin2 = h2buf + rd * (B_ * H_);  // h2[s-2]

  __shared__ _Float16 As[64 * 40];     // 64 rows x 32 k, pitch 40 (80B) anti-conflict
  __shared__ _Float16 Bs[64 * 40];
  __shared__ float gl[64 * 65];        // gates, pitch 65

  const int tid = threadIdx.x;
  const int lr = tid >> 2;             // staging row/col within tile (0..63)
  const int kc = (tid & 3) * 8;        // staging k offset (0,8,16,24)
  // weight row for tile col lr : gate = lr>>4, j = lr&15
  const size_t wrow_off = (size_t)((lr >> 4) * H_ + h0c + (lr & 15)) * K;

  floatx4 acc[2][2] = {};
  const int w = tid >> 6, lane = tid & 63;
  const int wm = (w >> 1) * 32, wn = (w & 1) * 32;
  const int l15 = lane & 15, kg = (lane >> 4) * 8;

  for (int ki = 0; ki < nk; ++ki) {
    const int k = (ki << 5) + kc;
    // ---- stage A tile (activations) ----
    half8 av;
    if (layer == 0 && k < I_) {
      const float* src = ctx + (size_t)(row0 + lr) * (T_ * I_) + (size_t)s * I_ + k;
      #pragma unroll
      for (int j = 0; j < 8; ++j) av[j] = (_Float16)src[j];
    } else {
      const _Float16* hs;
      if (layer == 0) hs = hin1 + (row0 + lr) * H_ + (k - I_);
      else hs = (k < H_) ? (hin1 + (row0 + lr) * H_ + k)
                         : (hin2 + (row0 + lr) * H_ + (k - H_));
      av = *(const half8*)hs;
    }
    *(half8*)(As + lr * 40 + kc) = av;
    // ---- stage B tile (weights, [n][k] row-major == B^T) ----
    half8 bv = *(const half8*)(Wc + wrow_off + k);
    *(half8*)(Bs + lr * 40 + kc) = bv;
    __syncthreads();
    // ---- MFMA: wave (wm,wn) 32x32 = 2x2 frags of 16x16, K=32 per stage ----
    half8 bf0 = *(const half8*)(Bs + (wn + l15) * 40 + kg);
    half8 bf1 = *(const half8*)(Bs + (wn + 16 + l15) * 40 + kg);
    #pragma unroll
    for (int m = 0; m < 2; ++m) {
      half8 af = *(const half8*)(As + (wm + 16 * m + l15) * 40 + kg);
      acc[m][0] = __builtin_amdgcn_mfma_f32_16x16x32_f16(af, bf0, acc[m][0], 0, 0, 0);
      acc[m][1] = __builtin_amdgcn_mfma_f32_16x16x32_f16(af, bf1, acc[m][1], 0, 0, 0);
    }
    __syncthreads();
  }

  // ---- spill gates to LDS: C/D layout col=lane&15, row=4*(lane>>4)+reg ----
  #pragma unroll
  for (int m = 0; m < 2; ++m) {
    #pragma unroll
    for (int n = 0; n < 2; ++n) {
      const int col = wn + 16 * n + l15;
      const int rowb = wm + 16 * m + (lane >> 4) * 4;
      #pragma unroll
      for (int r = 0; r < 4; ++r) gl[(rowb + r) * 65 + col] = acc[m][n][r];
    }
  }
  __syncthreads();

  // ---- fused LSTM cell update: 64 rows x 16 h per block ----
  const float* __restrict__ bih = layer ? bih1 : bih0;
  const float* __restrict__ bhh = layer ? bhh1 : bhh0;
  float* __restrict__ cbuf = layer ? c1buf : c0buf;
  #pragma unroll
  for (int q = 0; q < 4; ++q) {
    const int idx = tid + q * 256;
    const int r = idx >> 4, j = idx & 15;
    const int hg = h0c + j;
    const int brow = row0 + r;
    float gi = gl[r * 65 + j]      + bih[hg]           + bhh[hg];
    float gf = gl[r * 65 + 16 + j] + bih[H_ + hg]      + bhh[H_ + hg];
    float gg = gl[r * 65 + 32 + j] + bih[2 * H_ + hg]  + bhh[2 * H_ + hg];
    float go = gl[r * 65 + 48 + j] + bih[3 * H_ + hg]  + bhh[3 * H_ + hg];
    const float si = 1.f / (1.f + expf(-gi));
    const float sf = 1.f / (1.f + expf(-gf));
    const float so = 1.f / (1.f + expf(-go));
    const float tg = tanhf(gg);
    const float cp = cbuf[brow * H_ + hg];
    const float cn = sf * cp + si * tg;
    const float hn = so * tanhf(cn);
    cbuf[brow * H_ + hg] = cn;
    if (layer == 0) {
      h1buf[wr * (B_ * H_) + brow * H_ + hg] = (_Float16)hn;
    } else {
      h2buf[wr * (B_ * H_) + brow * H_ + hg] = (_Float16)hn;
      hF1[brow * H_ + hg] = hn;   // fp32 copy for readout (holds t=255 at end)
    }
  }
}

// ---- readout: out[b] = h2_last[b,:] . W_ro + b_ro ----
__global__ __launch_bounds__(256) void readout(
    const float* __restrict__ hF1, const float* __restrict__ Wro,
    const float* __restrict__ bro, float* __restrict__ out) {
  const int b = blockIdx.x;
  const int tid = threadIdx.x;
  float p = 0.f;
  for (int h = tid; h < H_; h += 256) p += hF1[b * H_ + h] * Wro[h];
  #pragma unroll
  for (int off = 32; off; off >>= 1) p += __shfl_down(p, off, 64);
  __shared__ float red[4];
  if ((tid & 63) == 0) red[tid >> 6] = p;
  __syncthreads();
  if (tid == 0) out[b] = red[0] + red[1] + red[2] + red[3] + bro[0];
}

extern "C" void kernel_launch(void* const* d_in, const int* in_sizes, int n_in,
                              void* d_out, int out_size, void* d_ws, size_t ws_size,
                              hipStream_t stream) {
  const float* init_hidden = (const float*)d_in[0];
  const float* ctx   = (const float*)d_in[1];
  const float* W_ih0 = (const float*)d_in[2];
  const float* W_hh0 = (const float*)d_in[3];
  const float* b_ih0 = (const float*)d_in[4];
  const float* b_hh0 = (const float*)d_in[5];
  const float* W_ih1 = (const float*)d_in[6];
  const float* W_hh1 = (const float*)d_in[7];
  const float* b_ih1 = (const float*)d_in[8];
  const float* b_hh1 = (const float*)d_in[9];
  const float* W_ro  = (const float*)d_in[10];
  const float* b_ro  = (const float*)d_in[11];

  char* ws = (char*)d_ws;
  _Float16* Wc0   = (_Float16*)(ws);                 // 4096*1536*2 = 12,582,912
  _Float16* Wc1   = (_Float16*)(ws + 12582912);      // 4096*2048*2 = 16,777,216
  _Float16* h1buf = (_Float16*)(ws + 29360128);      // 2 * 524,288
  _Float16* h2buf = (_Float16*)(ws + 30408704);      // 2 * 524,288
  float*    c0    = (float*)(ws + 31457280);         // 1,048,576
  float*    c1    = (float*)(ws + 32505856);         // 1,048,576
  float*    hF1   = (float*)(ws + 33554432);         // 1,048,576 (end ~34.6 MB)

  prep_wcat<<<dim3(K0 / 256, G4H), 256, 0, stream>>>(Wc0, W_ih0, W_hh0, I_, K0, I_, H_);
  prep_wcat<<<dim3(K1 / 256, G4H), 256, 0, stream>>>(Wc1, W_ih1, W_hh1, H_, K1, H_, H_);
  prep_state<<<dim3(B_ * H_ / 256), 256, 0, stream>>>(init_hidden, h1buf, h2buf, c0, c1);
  for (int s = 0; s <= T_; ++s)
    lstm_step<<<dim3(512), 256, 0, stream>>>(ctx, Wc0, Wc1, h1buf, h2buf, c0, c1, hF1,
                                             b_ih0, b_hh0, b_ih1, b_hh1, s);
  readout<<<dim3(B_), 256, 0, stream>>>(hF1, W_ro, b_ro, (float*)d_out);
}

// Round 2
// 5970.894 us; speedup vs baseline: 1.5971x; 1.5971x over previous
//
#include <hip/hip_runtime.h>
#include <hip/hip_bf16.h>

#define B_ 256
#define T_ 256
#define I_ 512
#define H_ 1024
#define CH 8          // chunk length (timesteps)
#define NCH 32        // number of chunks (T_/CH)

typedef _Float16 half8 __attribute__((ext_vector_type(8)));
typedef float floatx4 __attribute__((ext_vector_type(4)));

// Permuted gate-row order: n' -> orig row g*H + h, with g=(n'&63)>>4, h=(n'>>6)*16+(n'&15).
// Every 64-column slice = 16 h-units x 4 gates (i,f,g,o) -> cell update is block-local.

// ---- prep: permute + convert weights to f16, layout [4096][K] ----
__global__ __launch_bounds__(256) void prep_w(
    _Float16* __restrict__ dst, const float* __restrict__ src, int K) {
  const int np = blockIdx.y;
  const int k = blockIdx.x * 256 + threadIdx.x;
  const int cc = np & 63, g = cc >> 4, j = cc & 15;
  const int orig = g * H_ + (np >> 6) * 16 + j;
  dst[(size_t)np * K + k] = (_Float16)src[(size_t)orig * K + k];
}

__global__ __launch_bounds__(256) void prep_bias(
    float* __restrict__ bs0, float* __restrict__ bs1,
    const float* __restrict__ bih0, const float* __restrict__ bhh0,
    const float* __restrict__ bih1, const float* __restrict__ bhh1) {
  const int np = blockIdx.x * 256 + threadIdx.x;   // grid 16
  const int cc = np & 63, g = cc >> 4, j = cc & 15;
  const int orig = g * H_ + (np >> 6) * 16 + j;
  bs0[np] = bih0[orig] + bhh0[orig];
  bs1[np] = bih1[orig] + bhh1[orig];
}

__global__ __launch_bounds__(256) void prep_state(
    const float* __restrict__ init, _Float16* __restrict__ h1s,
    _Float16* __restrict__ h2s, float* __restrict__ c0, float* __restrict__ c1) {
  const int idx = blockIdx.x * 256 + threadIdx.x;   // grid B_*H_/256
  const float v = init[idx];
  h1s[B_ * H_ + idx] = (_Float16)v;   // parity slot 1 (t=0 reads slot 1)
  h2s[B_ * H_ + idx] = (_Float16)v;
  c0[idx] = 0.f;
  c1[idx] = 0.f;
}

// ---- batched xg GEMM: out[i*256+b][4096] (f16, permuted cols, bias added) ----
// AMODE 0: A = ctx fp32, row r -> ctx[(b*T + tbase + i)*I_], KK=512
// AMODE 1: A = h1chunk f16 contiguous rows, KK=1024
template<int KK, int AMODE>
__global__ __launch_bounds__(256, 2) void gemm_xg(
    const void* __restrict__ Ap, const _Float16* __restrict__ Bw,
    const float* __restrict__ bias, _Float16* __restrict__ out, int tbase) {
  constexpr int NST = KK / 64;
  __shared__ _Float16 As[2][128 * 72];
  __shared__ _Float16 Bs[2][128 * 72];
  const int tid = threadIdx.x;
  const int row0 = blockIdx.x * 128, col0 = blockIdx.y * 128;
  const int sr = tid >> 1, sc = (tid & 1) * 32;    // staging row / half-col base
  const int gr = row0 + sr;
  const size_t arow = (AMODE == 0)
      ? ((size_t)(gr & 255) * T_ + (size_t)tbase + (gr >> 8)) * I_
      : (size_t)gr * KK;
  const float*    af32 = (const float*)Ap + arow + sc;
  const _Float16* af16 = (const _Float16*)Ap + arow + sc;
  const _Float16* bsrc = Bw + (size_t)(col0 + sr) * KK + sc;

  const int w = tid >> 6, lane = tid & 63;
  const int wm = (w >> 1) * 64, wn = (w & 1) * 64;
  const int l15 = lane & 15, kg = (lane >> 4) * 8;
  floatx4 acc[4][4] = {};
  half8 ar[4], br[4];

  auto load_stage = [&](int ki) {
    const int k = ki * 64;
    #pragma unroll
    for (int c = 0; c < 4; ++c) {
      if (AMODE == 0) {
        float4 f0 = *(const float4*)(af32 + k + c * 8);
        float4 f1 = *(const float4*)(af32 + k + c * 8 + 4);
        half8 h;
        h[0] = (_Float16)f0.x; h[1] = (_Float16)f0.y;
        h[2] = (_Float16)f0.z; h[3] = (_Float16)f0.w;
        h[4] = (_Float16)f1.x; h[5] = (_Float16)f1.y;
        h[6] = (_Float16)f1.z; h[7] = (_Float16)f1.w;
        ar[c] = h;
      } else {
        ar[c] = *(const half8*)(af16 + k + c * 8);
      }
      br[c] = *(const half8*)(bsrc + k + c * 8);
    }
  };
  auto write_stage = [&](int buf) {
    #pragma unroll
    for (int c = 0; c < 4; ++c) *(half8*)(&As[buf][sr * 72 + sc + c * 8]) = ar[c];
    #pragma unroll
    for (int c = 0; c < 4; ++c) *(half8*)(&Bs[buf][sr * 72 + sc + c * 8]) = br[c];
  };

  load_stage(0); write_stage(0); __syncthreads();
  for (int ki = 0; ki < NST; ++ki) {
    const int cur = ki & 1;
    if (ki + 1 < NST) load_stage(ki + 1);
    #pragma unroll
    for (int ks = 0; ks < 2; ++ks) {
      half8 bf[4];
      #pragma unroll
      for (int n = 0; n < 4; ++n)
        bf[n] = *(const half8*)(&Bs[cur][(wn + 16 * n + l15) * 72 + ks * 32 + kg]);
      #pragma unroll
      for (int m = 0; m < 4; ++m) {
        half8 af = *(const half8*)(&As[cur][(wm + 16 * m + l15) * 72 + ks * 32 + kg]);
        #pragma unroll
        for (int n = 0; n < 4; ++n)
          acc[m][n] = __builtin_amdgcn_mfma_f32_16x16x32_f16(af, bf[n], acc[m][n], 0, 0, 0);
      }
    }
    if (ki + 1 < NST) write_stage(cur ^ 1);
    __syncthreads();
  }

  const int crow = (lane >> 4) * 4;
  #pragma unroll
  for (int n = 0; n < 4; ++n) {
    const int col = col0 + wn + 16 * n + l15;
    const float bv = bias[col];
    #pragma unroll
    for (int m = 0; m < 4; ++m) {
      const int rbase = row0 + wm + 16 * m + crow;
      #pragma unroll
      for (int r = 0; r < 4; ++r)
        out[(size_t)(rbase + r) * 4096 + col] = (_Float16)(acc[m][n][r] + bv);
    }
  }
}

// ---- fused recurrent step: blocks 0..255 L0 @ t0, 256..511 L1 @ t1; K=1024 ----
__global__ __launch_bounds__(256, 2) void lstm_step(
    const _Float16* __restrict__ Wh0, const _Float16* __restrict__ Wh1,
    const _Float16* __restrict__ xg0, const _Float16* __restrict__ xg1,
    _Float16* __restrict__ h1s, _Float16* __restrict__ h2s,
    _Float16* __restrict__ h1chunk, float* __restrict__ c0buf,
    float* __restrict__ c1buf, float* __restrict__ hF, int t0, int t1, int ci) {
  const int layer = blockIdx.x >> 8;
  const int t = layer ? t1 : t0;
  if (t < 0) return;
  const int tb = blockIdx.x & 255;
  const int row0 = (tb >> 6) * 64;
  const int nb = tb & 63;
  const int col0 = nb * 64;
  const _Float16* __restrict__ Wh = layer ? Wh1 : Wh0;
  const _Float16* __restrict__ xg = (layer ? xg1 : xg0) + (size_t)ci * 256 * 4096;
  _Float16* __restrict__ hs = layer ? h2s : h1s;
  float* __restrict__ cbuf = layer ? c1buf : c0buf;
  const int rd = (t + 1) & 1, wr = t & 1;
  const _Float16* __restrict__ hin = hs + rd * (B_ * H_);

  // LDS: As[2 dbuf][2 khalf][64*72] + Bs same; gl (f32 64x68) overlays after K-loop
  __shared__ _Float16 lds[2 * (2 * 2 * 64 * 72)];
  _Float16* As = lds;
  _Float16* Bs = lds + 2 * 2 * 64 * 72;
  float* gl = (float*)lds;

  const int tid = threadIdx.x;
  const int sr = tid >> 2, kh_s = (tid >> 1) & 1, coff = (tid & 1) * 32;
  const _Float16* asrc = hin + (size_t)(row0 + sr) * H_ + kh_s * 512 + coff;
  const _Float16* bsrc = Wh + (size_t)(col0 + sr) * H_ + kh_s * 512 + coff;
  const int sdst = kh_s * (64 * 72) + sr * 72 + coff;

  const int w = tid >> 6, lane = tid & 63;
  const int rh = (w & 1) * 32, kh = w >> 1;   // row-half, k-half of this wave
  const int l15 = lane & 15, kg = (lane >> 4) * 8;
  floatx4 acc[2][4] = {};
  half8 ar[4], br[4];

  auto load_stage = [&](int ki) {
    #pragma unroll
    for (int c = 0; c < 4; ++c) ar[c] = *(const half8*)(asrc + ki * 64 + c * 8);
    #pragma unroll
    for (int c = 0; c < 4; ++c) br[c] = *(const half8*)(bsrc + ki * 64 + c * 8);
  };
  auto write_stage = [&](int buf) {
    _Float16* dA = As + buf * (2 * 64 * 72) + sdst;
    _Float16* dB = Bs + buf * (2 * 64 * 72) + sdst;
    #pragma unroll
    for (int c = 0; c < 4; ++c) *(half8*)(dA + c * 8) = ar[c];
    #pragma unroll
    for (int c = 0; c < 4; ++c) *(half8*)(dB + c * 8) = br[c];
  };

  load_stage(0); write_stage(0); __syncthreads();
  for (int ki = 0; ki < 8; ++ki) {
    const int cur = ki & 1;
    if (ki < 7) load_stage(ki + 1);
    const _Float16* Ab = As + cur * (2 * 64 * 72) + kh * (64 * 72);
    const _Float16* Bb = Bs + cur * (2 * 64 * 72) + kh * (64 * 72);
    #pragma unroll
    for (int ks = 0; ks < 2; ++ks) {
      half8 bf[4];
      #pragma unroll
      for (int n = 0; n < 4; ++n)
        bf[n] = *(const half8*)(Bb + (16 * n + l15) * 72 + ks * 32 + kg);
      #pragma unroll
      for (int m = 0; m < 2; ++m) {
        half8 af = *(const half8*)(Ab + (rh + 16 * m + l15) * 72 + ks * 32 + kg);
        #pragma unroll
        for (int n = 0; n < 4; ++n)
          acc[m][n] = __builtin_amdgcn_mfma_f32_16x16x32_f16(af, bf[n], acc[m][n], 0, 0, 0);
      }
    }
    if (ki < 7) write_stage(cur ^ 1);
    __syncthreads();
  }

  // reduce the two k-halves into gl
  const int crow = (lane >> 4) * 4;
  if (kh == 0) {
    #pragma unroll
    for (int m = 0; m < 2; ++m)
      #pragma unroll
      for (int n = 0; n < 4; ++n) {
        const int col = 16 * n + l15, rowl = rh + 16 * m + crow;
        #pragma unroll
        for (int r = 0; r < 4; ++r) gl[(rowl + r) * 68 + col] = acc[m][n][r];
      }
  }
  __syncthreads();
  if (kh == 1) {
    #pragma unroll
    for (int m = 0; m < 2; ++m)
      #pragma unroll
      for (int n = 0; n < 4; ++n) {
        const int col = 16 * n + l15, rowl = rh + 16 * m + crow;
        #pragma unroll
        for (int r = 0; r < 4; ++r) gl[(rowl + r) * 68 + col] += acc[m][n][r];
      }
  }
  __syncthreads();

  // cell update: 64 rows x 16 h-units
  #pragma unroll
  for (int q = 0; q < 4; ++q) {
    const int idx = tid + q * 256;
    const int r = idx >> 4, j = idx & 15;
    const int brow = row0 + r;
    const int hu = nb * 16 + j;
    const _Float16* xr = xg + (size_t)brow * 4096 + col0;
    float gi = gl[r * 68 + j]          + (float)xr[j];
    float gf = gl[r * 68 + 16 + j]     + (float)xr[16 + j];
    float gg = gl[r * 68 + 32 + j]     + (float)xr[32 + j];
    float go = gl[r * 68 + 48 + j]     + (float)xr[48 + j];
    const float si = 1.f / (1.f + expf(-gi));
    const float sf = 1.f / (1.f + expf(-gf));
    const float so = 1.f / (1.f + expf(-go));
    const float tg = tanhf(gg);
    const float cp = cbuf[(size_t)brow * H_ + hu];
    const float cn = sf * cp + si * tg;
    const float hn = so * tanhf(cn);
    cbuf[(size_t)brow * H_ + hu] = cn;
    hs[wr * (B_ * H_) + (size_t)brow * H_ + hu] = (_Float16)hn;
    if (layer == 0)
      h1chunk[((size_t)ci * 256 + brow) * H_ + hu] = (_Float16)hn;
    else
      hF[(size_t)brow * H_ + hu] = hn;
  }
}

// ---- readout: out[b] = hF[b,:] . W_ro + b_ro ----
__global__ __launch_bounds__(256) void readout(
    const float* __restrict__ hF, const float* __restrict__ Wro,
    const float* __restrict__ bro, float* __restrict__ out) {
  const int b = blockIdx.x;
  const int tid = threadIdx.x;
  float p = 0.f;
  for (int h = tid; h < H_; h += 256) p += hF[(size_t)b * H_ + h] * Wro[h];
  #pragma unroll
  for (int off = 32; off; off >>= 1) p += __shfl_down(p, off, 64);
  __shared__ float red[4];
  if ((tid & 63) == 0) red[tid >> 6] = p;
  __syncthreads();
  if (tid == 0) out[b] = red[0] + red[1] + red[2] + red[3] + bro[0];
}

extern "C" void kernel_launch(void* const* d_in, const int* in_sizes, int n_in,
                              void* d_out, int out_size, void* d_ws, size_t ws_size,
                              hipStream_t stream) {
  const float* init_hidden = (const float*)d_in[0];
  const float* ctx   = (const float*)d_in[1];
  const float* W_ih0 = (const float*)d_in[2];
  const float* W_hh0 = (const float*)d_in[3];
  const float* b_ih0 = (const float*)d_in[4];
  const float* b_hh0 = (const float*)d_in[5];
  const float* W_ih1 = (const float*)d_in[6];
  const float* W_hh1 = (const float*)d_in[7];
  const float* b_ih1 = (const float*)d_in[8];
  const float* b_hh1 = (const float*)d_in[9];
  const float* W_ro  = (const float*)d_in[10];
  const float* b_ro  = (const float*)d_in[11];

  char* ws = (char*)d_ws;
  _Float16* W0p  = (_Float16*)(ws);                  // 4096*512*2  = 4,194,304
  _Float16* Wh0p = (_Float16*)(ws + 4194304);        // 4096*1024*2 = 8,388,608
  _Float16* W1p  = (_Float16*)(ws + 12582912);       // 8,388,608
  _Float16* Wh1p = (_Float16*)(ws + 20971520);       // 8,388,608
  float*    bs0  = (float*)(ws + 29360128);          // 16,384
  float*    bs1  = (float*)(ws + 29376512);          // 16,384
  _Float16* xg0  = (_Float16*)(ws + 29392896);       // 8*256*4096*2 = 16,777,216
  _Float16* xg1  = (_Float16*)(ws + 46170112);       // 16,777,216
  _Float16* h1c  = (_Float16*)(ws + 62947328);       // 2048*1024*2 = 4,194,304
  _Float16* h1s  = (_Float16*)(ws + 67141632);       // 1,048,576
  _Float16* h2s  = (_Float16*)(ws + 68190208);       // 1,048,576
  float*    c0   = (float*)(ws + 69238784);          // 1,048,576
  float*    c1   = (float*)(ws + 70287360);          // 1,048,576
  float*    hF   = (float*)(ws + 71335936);          // 1,048,576 -> end 72,384,512

  prep_w<<<dim3(I_ / 256, 4096), 256, 0, stream>>>(W0p, W_ih0, I_);
  prep_w<<<dim3(H_ / 256, 4096), 256, 0, stream>>>(Wh0p, W_hh0, H_);
  prep_w<<<dim3(H_ / 256, 4096), 256, 0, stream>>>(W1p, W_ih1, H_);
  prep_w<<<dim3(H_ / 256, 4096), 256, 0, stream>>>(Wh1p, W_hh1, H_);
  prep_bias<<<dim3(16), 256, 0, stream>>>(bs0, bs1, b_ih0, b_hh0, b_ih1, b_hh1);
  prep_state<<<dim3(B_ * H_ / 256), 256, 0, stream>>>(init_hidden, h1s, h2s, c0, c1);

  for (int c = 0; c <= NCH; ++c) {
    if (c < NCH)
      gemm_xg<512, 0><<<dim3(16, 32), 256, 0, stream>>>(ctx, W0p, bs0, xg0, c * CH);
    if (c >= 1)
      gemm_xg<1024, 1><<<dim3(16, 32), 256, 0, stream>>>(h1c, W1p, bs1, xg1, 0);
    for (int i = 0; i < CH; ++i) {
      const int t0 = (c < NCH) ? c * CH + i : -1;
      const int t1 = (c >= 1) ? (c - 1) * CH + i : -1;
      lstm_step<<<dim3(512), 256, 0, stream>>>(Wh0p, Wh1p, xg0, xg1, h1s, h2s,
                                               h1c, c0, c1, hF, t0, t1, i);
    }
  }
  readout<<<dim3(B_), 256, 0, stream>>>(hF, W_ro, b_ro, (float*)d_out);
}